// Round 1
// baseline (242.312 us; speedup 1.0000x reference)
//
#include <hip/hip_runtime.h>
#include <cstdint>
#include <cstddef>

#define NTOT 22743      // 1083 + 4332 + 17328
#define N1   1083
#define N12  5415
#define BATCH 64
#define KCAND 512
#define MAXPC 100
#define MAXTOT 100

__device__ __forceinline__ float sigmoidf(float x) { return 1.0f / (1.0f + expf(-x)); }

// ---------------------------------------------------------------- kernel 1
// scoresT[b][c][i] = sigmoid(obj) * sigmoid(cls_c), contiguous per (b,c)
__global__ __launch_bounds__(256) void score_kernel(
    const float* __restrict__ p1, const float* __restrict__ p2,
    const float* __restrict__ p3, float* __restrict__ scoresT)
{
  int u = blockIdx.x * 256 + threadIdx.x;
  if (u >= BATCH * NTOT) return;
  int b = u / NTOT;
  int i = u - b * NTOT;
  const float* p; int local, per;
  if (i < N1)       { p = p1; local = i;        per = 1083; }
  else if (i < N12) { p = p2; local = i - N1;   per = 4332; }
  else              { p = p3; local = i - N12;  per = 17328; }
  const float* q = p + ((size_t)b * per + local) * 7;
  float obj = sigmoidf(q[4]);
  float s0 = obj * sigmoidf(q[5]);
  float s1 = obj * sigmoidf(q[6]);
  scoresT[(size_t)(b * 2 + 0) * NTOT + i] = s0;
  scoresT[(size_t)(b * 2 + 1) * NTOT + i] = s1;
}

// box decode for global candidate index i of image b
__device__ void decode_box(const float* __restrict__ p1, const float* __restrict__ p2,
                           const float* __restrict__ p3, const float* __restrict__ anch,
                           int b, int i, float bb[4])
{
  const float* p; int local, g, abase, per;
  if (i < N1)       { p = p1; local = i;       g = 19; abase = 6; per = 1083; }
  else if (i < N12) { p = p2; local = i - N1;  g = 38; abase = 3; per = 4332; }
  else              { p = p3; local = i - N12; g = 76; abase = 0; per = 17328; }
  const float* q = p + ((size_t)b * per + local) * 7;
  int a    = local % 3;
  int cell = local / 3;
  int col  = cell % g;
  int row  = cell / g;
  float aw = anch[(abase + a) * 2 + 0];
  float ah = anch[(abase + a) * 2 + 1];
  float x = (sigmoidf(q[0]) + (float)col) / (float)g;
  float y = (sigmoidf(q[1]) + (float)row) / (float)g;
  float w = expf(q[2]) * aw;
  float h = expf(q[3]) * ah;
  float x1 = x - w * 0.5f;
  float y1 = y - h * 0.5f;
  bb[0] = x1; bb[1] = y1; bb[2] = x1 + w; bb[3] = y1 + h;
}

// ---------------------------------------------------------------- kernel 2
// one block per (image, class): exact top-512 (radix select + bitonic sort,
// ties by ascending index like lax.top_k), decode boxes, greedy NMS on wave 0,
// compact first <=100 kept into workspace.
__global__ __launch_bounds__(256) void nms_kernel(
    const float* __restrict__ sT,
    const float* __restrict__ p1, const float* __restrict__ p2,
    const float* __restrict__ p3, const float* __restrict__ anch,
    float* __restrict__ selScore, float* __restrict__ selBox,
    int* __restrict__ selRank, int* __restrict__ selCount)
{
  const int bc  = blockIdx.x;   // b*2 + c
  const int b   = bc >> 1;
  const int tid = threadIdx.x;
  const uint32_t* keys = (const uint32_t*)(sT + (size_t)bc * NTOT); // positive floats: bit order == value order

  __shared__ uint32_t hist[256];
  __shared__ uint32_t skey[1024];
  __shared__ uint32_t sidx[1024];
  __shared__ float    bxs[512][4];
  __shared__ float    sarea[512];
  __shared__ uint32_t keepA[512];
  __shared__ uint32_t svar[8];

  if (tid == 0) { svar[0] = 0u; svar[1] = 0u; svar[2] = KCAND; svar[3] = 0u; svar[4] = 0u; }
  __syncthreads();

  // ---- radix select: find exact key value K of the 512th largest
  for (int pass = 0; pass < 4; pass++) {
    const int shift = 24 - 8 * pass;
    hist[tid] = 0u;
    __syncthreads();
    const uint32_t prefix = svar[0], mask = svar[1];
    for (int i = tid; i < NTOT; i += 256) {
      uint32_t k = keys[i];
      if ((k & mask) == prefix) atomicAdd(&hist[(k >> shift) & 255u], 1u);
    }
    __syncthreads();
    if (tid == 0) {
      uint32_t nd = svar[2];
      int v = 255;
      for (;; v--) {
        uint32_t cc = hist[v];
        if (cc >= nd || v == 0) break;
        nd -= cc;
      }
      svar[0] = prefix | ((uint32_t)v << shift);
      svar[1] = mask | (255u << shift);
      svar[2] = nd;
    }
    __syncthreads();
  }
  const uint32_t K = svar[0];

  // ---- collect all candidates with key >= K (count in [512, 512+ties))
  for (int r = tid; r < 1024; r += 256) { skey[r] = 0u; sidx[r] = 0xFFFFFFFFu; }
  __syncthreads();
  for (int i = tid; i < NTOT; i += 256) {
    uint32_t k = keys[i];
    if (k >= K) {
      uint32_t pos = atomicAdd(&svar[3], 1u);
      if (pos < 1024u) { skey[pos] = k; sidx[pos] = (uint32_t)i; }
    }
  }
  __syncthreads();

  // ---- bitonic sort 1024: descending by key, ties ascending by index
  for (int kk = 2; kk <= 1024; kk <<= 1) {
    for (int j = kk >> 1; j > 0; j >>= 1) {
      for (int t = tid; t < 1024; t += 256) {
        int ixj = t ^ j;
        if (ixj > t) {
          uint32_t ka = skey[t], kb = skey[ixj];
          uint32_t ia = sidx[t], ib = sidx[ixj];
          bool aLess = (ka < kb) || (ka == kb && ia > ib);
          if (((t & kk) == 0) ? aLess : !aLess) {
            skey[t] = kb; skey[ixj] = ka;
            sidx[t] = ib; sidx[ixj] = ia;
          }
        }
      }
      __syncthreads();
    }
  }

  // ---- decode top-512 boxes; count how many pass the score threshold
  for (int r = tid; r < KCAND; r += 256) {
    float bb[4] = {0.f, 0.f, 0.f, 0.f};
    float sc = 0.f;
    if (sidx[r] != 0xFFFFFFFFu) {
      decode_box(p1, p2, p3, anch, b, (int)sidx[r], bb);
      sc = __uint_as_float(skey[r]);
    }
    bxs[r][0] = bb[0]; bxs[r][1] = bb[1]; bxs[r][2] = bb[2]; bxs[r][3] = bb[3];
    sarea[r] = fmaxf(bb[2] - bb[0], 0.f) * fmaxf(bb[3] - bb[1], 0.f);
    keepA[r] = 0u;
    if (sc > 0.5f) atomicAdd(&svar[4], 1u);   // scores sorted desc -> count == prefix length
  }
  __syncthreads();

  // ---- greedy NMS on wave 0; per-lane keep bitmask (bit t <-> index t*64+lane)
  if (tid < 64) {
    const int lane  = tid;
    const int limit = (int)svar[4];
    uint32_t keepbits = 0u;
    int kept = 0;
    for (int i = 0; i < limit; i++) {
      float ix1 = bxs[i][0], iy1 = bxs[i][1], ix2 = bxs[i][2], iy2 = bxs[i][3];
      float iar = sarea[i];
      bool any = false;
      int tmax = (i - 1) >> 6;
      for (int t = 0; t <= tmax; t++) {
        int j = t * 64 + lane;
        if (j < i && ((keepbits >> t) & 1u)) {
          float iw = fminf(ix2, bxs[j][2]) - fmaxf(ix1, bxs[j][0]);
          float ih = fminf(iy2, bxs[j][3]) - fmaxf(iy1, bxs[j][1]);
          iw = fmaxf(iw, 0.f); ih = fmaxf(ih, 0.f);
          float inter = iw * ih;
          float uni = iar + sarea[j] - inter;
          any |= ((inter / fmaxf(uni, 1e-9f)) > 0.5f);
        }
      }
      bool sup = __any(any);
      if (!sup) {
        if (lane == (i & 63)) keepbits |= (1u << (i >> 6));
        kept++;
        if (kept >= MAXPC) break;   // cumsum(keep)<=100 drops later ones anyway
      }
    }
    for (int t = 0; t < 8; t++) keepA[t * 64 + lane] = (keepbits >> t) & 1u;
  }
  __syncthreads();

  // ---- compact kept entries (order preserved) into workspace
  if (tid == 0) {
    uint32_t cnt = 0;
    for (int r = 0; r < KCAND; r++) {
      if (keepA[r]) { sidx[r] = cnt; cnt++; }   // reuse sidx as position
    }
    if (cnt > MAXPC) cnt = MAXPC;
    selCount[bc] = (int)cnt;
  }
  __syncthreads();
  for (int r = tid; r < KCAND; r += 256) {
    if (keepA[r]) {
      uint32_t p = sidx[r];
      if (p < MAXPC) {
        selScore[bc * MAXPC + p] = __uint_as_float(skey[r]);
        selRank[bc * MAXPC + p]  = r;
        float* o = &selBox[(size_t)(bc * MAXPC + p) * 4];
        o[0] = bxs[r][0]; o[1] = bxs[r][1]; o[2] = bxs[r][2]; o[3] = bxs[r][3];
      }
    }
  }
}

// ---------------------------------------------------------------- kernel 3
// per image: merge the two class lists (<=200 entries), exact top-100 by
// (score desc, flat index asc), write boxes/scores/classes/count.
__global__ __launch_bounds__(256) void merge_kernel(
    const float* __restrict__ selScore, const float* __restrict__ selBox,
    const int* __restrict__ selRank, const int* __restrict__ selCount,
    float* __restrict__ out)
{
  const int b   = blockIdx.x;
  const int tid = threadIdx.x;
  __shared__ float    es[256];
  __shared__ uint32_t ek[256];
  __shared__ float    eb[256][4];
  const int c0 = selCount[b * 2 + 0];
  const int c1 = selCount[b * 2 + 1];

  float s = -1.0f; uint32_t fk = 0xFFFFFFFFu;
  float bb[4] = {0.f, 0.f, 0.f, 0.f};
  if (tid < c0 + c1) {
    int cls  = (tid < c0) ? 0 : 1;
    int slot = (cls == 0) ? tid : (tid - c0);
    int src  = (b * 2 + cls) * MAXPC + slot;
    s  = selScore[src];
    fk = (uint32_t)(cls * KCAND + selRank[src]);   // flat index in (2,512) array
    bb[0] = selBox[(size_t)src * 4 + 0]; bb[1] = selBox[(size_t)src * 4 + 1];
    bb[2] = selBox[(size_t)src * 4 + 2]; bb[3] = selBox[(size_t)src * 4 + 3];
  }
  es[tid] = s; ek[tid] = fk;
  eb[tid][0] = bb[0]; eb[tid][1] = bb[1]; eb[tid][2] = bb[2]; eb[tid][3] = bb[3];
  __syncthreads();

  for (int kk = 2; kk <= 256; kk <<= 1) {
    for (int j = kk >> 1; j > 0; j >>= 1) {
      int ixj = tid ^ j;
      if (ixj > tid) {
        float sa = es[tid], sb = es[ixj];
        uint32_t fa = ek[tid], fb = ek[ixj];
        bool aLess = (sa < sb) || (sa == sb && fa > fb);
        if (((tid & kk) == 0) ? aLess : !aLess) {
          es[tid] = sb; es[ixj] = sa;
          ek[tid] = fb; ek[ixj] = fa;
          for (int d = 0; d < 4; d++) { float tmp = eb[tid][d]; eb[tid][d] = eb[ixj][d]; eb[ixj][d] = tmp; }
        }
      }
      __syncthreads();
    }
  }

  float* outBoxes  = out;
  float* outScores = out + (size_t)BATCH * MAXTOT * 4;
  float* outCls    = outScores + (size_t)BATCH * MAXTOT;
  float* outCnt    = outCls + (size_t)BATCH * MAXTOT;

  if (tid < MAXTOT) {
    float sc = es[tid];
    bool kept = sc > 0.0f;
    outScores[b * MAXTOT + tid] = kept ? sc : 0.0f;
    outCls[b * MAXTOT + tid]    = kept ? (float)(ek[tid] >> 9) : 0.0f;
    float* ob = &outBoxes[(size_t)(b * MAXTOT + tid) * 4];
    for (int d = 0; d < 4; d++) {
      float v = fminf(fmaxf(eb[tid][d], 0.f), 1.f);
      ob[d] = kept ? v : 0.0f;
    }
  }
  if (tid == 0) {
    int total = c0 + c1; if (total > MAXTOT) total = MAXTOT;
    outCnt[b] = (float)total;
  }
}

// ---------------------------------------------------------------- launch
extern "C" void kernel_launch(void* const* d_in, const int* in_sizes, int n_in,
                              void* d_out, int out_size, void* d_ws, size_t ws_size,
                              hipStream_t stream)
{
  const float* p1   = (const float*)d_in[0];
  const float* p2   = (const float*)d_in[1];
  const float* p3   = (const float*)d_in[2];
  const float* anch = (const float*)d_in[3];

  float* ws       = (float*)d_ws;
  float* scoresT  = ws;                                        // 64*2*22743 f32
  float* selScore = scoresT + (size_t)BATCH * 2 * NTOT;        // 128*100 f32
  float* selBox   = selScore + BATCH * 2 * MAXPC;              // 128*100*4 f32
  int*   selRank  = (int*)(selBox + (size_t)BATCH * 2 * MAXPC * 4);
  int*   selCount = selRank + BATCH * 2 * MAXPC;               // 128 int

  const int total = BATCH * NTOT;
  score_kernel<<<(total + 255) / 256, 256, 0, stream>>>(p1, p2, p3, scoresT);
  nms_kernel<<<BATCH * 2, 256, 0, stream>>>(scoresT, p1, p2, p3, anch,
                                            selScore, selBox, selRank, selCount);
  merge_kernel<<<BATCH, 256, 0, stream>>>(selScore, selBox, selRank, selCount,
                                          (float*)d_out);
}

// Round 2
// 86.566 us; speedup vs baseline: 2.7992x; 2.7992x over previous
//
#include <hip/hip_runtime.h>
#include <cstdint>
#include <cstddef>

#define NTOT  22743      // 1083 + 4332 + 17328
#define NTOTP 22744      // padded stride (16B-aligned rows for uint4 loads)
#define N1    1083
#define N12   5415
#define BATCH 64
#define KCAND 512
#define CAP   4096       // candidate capacity (scores > 0.5 ~ 1830 expected)
#define MAXPC 100
#define MAXTOT 100

__device__ __forceinline__ float sigmoidf(float x) { return 1.0f / (1.0f + expf(-x)); }

// ---------------------------------------------------------------- kernel 1
// scoresT[b][c][i] = sigmoid(obj) * sigmoid(cls_c), contiguous per (b,c), padded stride
__global__ __launch_bounds__(256) void score_kernel(
    const float* __restrict__ p1, const float* __restrict__ p2,
    const float* __restrict__ p3, float* __restrict__ scoresT)
{
  int u = blockIdx.x * 256 + threadIdx.x;
  if (u >= BATCH * NTOT) return;
  int b = u / NTOT;
  int i = u - b * NTOT;
  const float* p; int local, per;
  if (i < N1)       { p = p1; local = i;        per = 1083; }
  else if (i < N12) { p = p2; local = i - N1;   per = 4332; }
  else              { p = p3; local = i - N12;  per = 17328; }
  const float* q = p + ((size_t)b * per + local) * 7;
  float obj = sigmoidf(q[4]);
  float s0 = obj * sigmoidf(q[5]);
  float s1 = obj * sigmoidf(q[6]);
  scoresT[(size_t)(b * 2 + 0) * NTOTP + i] = s0;
  scoresT[(size_t)(b * 2 + 1) * NTOTP + i] = s1;
}

// box decode for global candidate index i of image b
__device__ void decode_box(const float* __restrict__ p1, const float* __restrict__ p2,
                           const float* __restrict__ p3, const float* __restrict__ anch,
                           int b, int i, float bb[4])
{
  const float* p; int local, g, abase, per;
  if (i < N1)       { p = p1; local = i;       g = 19; abase = 6; per = 1083; }
  else if (i < N12) { p = p2; local = i - N1;  g = 38; abase = 3; per = 4332; }
  else              { p = p3; local = i - N12; g = 76; abase = 0; per = 17328; }
  const float* q = p + ((size_t)b * per + local) * 7;
  int a    = local % 3;
  int cell = local / 3;
  int col  = cell % g;
  int row  = cell / g;
  float aw = anch[(abase + a) * 2 + 0];
  float ah = anch[(abase + a) * 2 + 1];
  float x = (sigmoidf(q[0]) + (float)col) / (float)g;
  float y = (sigmoidf(q[1]) + (float)row) / (float)g;
  float w = expf(q[2]) * aw;
  float h = expf(q[3]) * ah;
  float x1 = x - w * 0.5f;
  float y1 = y - h * 0.5f;
  bb[0] = x1; bb[1] = y1; bb[2] = x1 + w; bb[3] = y1 + h;
}

// ---------------------------------------------------------------- kernel 2
// one block (512 thr) per (image, class):
//  compact keys > 0.5 -> LDS radix-select 512th key -> sort 1024 ->
//  decode boxes -> register-kept-list NMS on wave 0 -> ballot compaction.
__global__ __launch_bounds__(512) void nms_kernel(
    const float* __restrict__ sT,
    const float* __restrict__ p1, const float* __restrict__ p2,
    const float* __restrict__ p3, const float* __restrict__ anch,
    float* __restrict__ selScore, float* __restrict__ selBox,
    int* __restrict__ selRank, int* __restrict__ selCount)
{
  const int bc  = blockIdx.x;   // b*2 + c
  const int b   = bc >> 1;
  const int tid = threadIdx.x;

  __shared__ uint32_t ckey[CAP];
  __shared__ uint32_t cidx[CAP];
  __shared__ uint32_t skey[1024];
  __shared__ uint32_t sidx[1024];
  __shared__ float    bxs[512][4];
  __shared__ float    sarea[512];
  __shared__ uint32_t pos[512];
  __shared__ uint32_t hist[256];
  __shared__ uint32_t svar[8];

  if (tid == 0) { svar[0] = 0x3F000000u; svar[2] = KCAND; svar[3] = 0u; svar[4] = 0u; }
  for (int r = tid; r < 1024; r += 512) { skey[r] = 0u; sidx[r] = 0xFFFFFFFFu; }
  __syncthreads();

  // ---- compact: all keys > 0.5f (bit pattern > 0x3F000000 for positive floats)
  const uint4* k4 = (const uint4*)(sT + (size_t)bc * NTOTP);
  for (int i4 = tid; i4 < NTOTP / 4; i4 += 512) {
    uint4 v = k4[i4];
    int base = i4 * 4;
    if (v.x > 0x3F000000u) { uint32_t q = atomicAdd(&svar[3], 1u); if (q < CAP) { ckey[q] = v.x; cidx[q] = base; } }
    if (v.y > 0x3F000000u) { uint32_t q = atomicAdd(&svar[3], 1u); if (q < CAP) { ckey[q] = v.y; cidx[q] = base + 1; } }
    if (v.z > 0x3F000000u) { uint32_t q = atomicAdd(&svar[3], 1u); if (q < CAP) { ckey[q] = v.z; cidx[q] = base + 2; } }
    if (v.w > 0x3F000000u && base + 3 < NTOT) { uint32_t q = atomicAdd(&svar[3], 1u); if (q < CAP) { ckey[q] = v.w; cidx[q] = base + 3; } }
  }
  __syncthreads();
  int n = (int)svar[3]; if (n > CAP) n = CAP;

  // ---- radix select (in LDS): exact key of the 512th largest
  // all candidate keys lie in (0x3F000000, 0x3F800000) -> top byte fixed 0x3F
  uint32_t K = 0u;
  if (n > KCAND) {
    #pragma unroll
    for (int p = 0; p < 3; p++) {
      const int shift = 16 - 8 * p;
      const uint32_t maskB = (p == 0) ? 0xFF000000u : (p == 1) ? 0xFFFF0000u : 0xFFFFFF00u;
      if (tid < 256) hist[tid] = 0u;
      __syncthreads();
      const uint32_t prefix = svar[0];
      for (int i = tid; i < n; i += 512) {
        uint32_t k = ckey[i];
        if ((k & maskB) == prefix) atomicAdd(&hist[(k >> shift) & 255u], 1u);
      }
      __syncthreads();
      if (tid < 64) {                       // wave-parallel suffix-scan select
        int lane = tid;
        uint32_t h0 = hist[lane * 4 + 0], h1 = hist[lane * 4 + 1];
        uint32_t h2 = hist[lane * 4 + 2], h3 = hist[lane * 4 + 3];
        uint32_t s3 = h3, s2 = h2 + s3, s1 = h1 + s2, s0 = h0 + s1;
        uint32_t acc = s0;
        #pragma unroll
        for (int off = 1; off < 64; off <<= 1) {
          uint32_t v = __shfl_down(acc, (unsigned)off);
          acc += (lane + off < 64) ? v : 0u;
        }
        uint32_t above = acc - s0;          // sum over bins >= (lane+1)*4
        uint32_t S0 = above + s0, S1 = above + s1, S2 = above + s2, S3 = above + s3, S4 = above;
        uint32_t nd = svar[2];
        if (S0 >= nd && S1 < nd) { svar[0] = prefix | ((uint32_t)(lane * 4 + 0) << shift); svar[2] = nd - S1; }
        if (S1 >= nd && S2 < nd) { svar[0] = prefix | ((uint32_t)(lane * 4 + 1) << shift); svar[2] = nd - S2; }
        if (S2 >= nd && S3 < nd) { svar[0] = prefix | ((uint32_t)(lane * 4 + 2) << shift); svar[2] = nd - S3; }
        if (S3 >= nd && S4 < nd) { svar[0] = prefix | ((uint32_t)(lane * 4 + 3) << shift); svar[2] = nd - S4; }
      }
      __syncthreads();
    }
    K = svar[0];
  }

  // ---- collect candidates with key >= K (exactly 512 when keys distinct)
  for (int i = tid; i < n; i += 512) {
    uint32_t k = ckey[i];
    if (k >= K) {
      uint32_t q = atomicAdd(&svar[4], 1u);
      if (q < 1024u) { skey[q] = k; sidx[q] = cidx[i]; }
    }
  }
  __syncthreads();

  // ---- bitonic sort 1024: descending by key, ties ascending by index
  for (int kk = 2; kk <= 1024; kk <<= 1) {
    for (int j = kk >> 1; j > 0; j >>= 1) {
      for (int t = tid; t < 1024; t += 512) {
        int ixj = t ^ j;
        if (ixj > t) {
          uint32_t ka = skey[t], kb = skey[ixj];
          uint32_t ia = sidx[t], ib = sidx[ixj];
          bool aLess = (ka < kb) || (ka == kb && ia > ib);
          if (((t & kk) == 0) ? aLess : !aLess) {
            skey[t] = kb; skey[ixj] = ka;
            sidx[t] = ib; sidx[ixj] = ia;
          }
        }
      }
      __syncthreads();
    }
  }

  const int limit = (n < KCAND) ? n : KCAND;   // all entries < limit have score > 0.5

  // ---- decode boxes for ranks [0, 512)
  if (tid < 512) {
    int r = tid;
    float bb[4] = {0.f, 0.f, 0.f, 0.f};
    if (r < limit) decode_box(p1, p2, p3, anch, b, (int)sidx[r], bb);
    bxs[r][0] = bb[0]; bxs[r][1] = bb[1]; bxs[r][2] = bb[2]; bxs[r][3] = bb[3];
    sarea[r] = fmaxf(bb[2] - bb[0], 0.f) * fmaxf(bb[3] - bb[1], 0.f);
  }
  __syncthreads();

  // ---- greedy NMS on wave 0; kept list lives in registers (2 slots/lane)
  if (tid < 64) {
    const int lane = tid;
    float k0x1 = 0.f, k0y1 = 0.f, k0x2 = 0.f, k0y2 = 0.f, k0a = 0.f;
    float k1x1 = 0.f, k1y1 = 0.f, k1x2 = 0.f, k1y2 = 0.f, k1a = 0.f;
    int kept = 0;
    uint32_t keepbits = 0u;
    float c0 = 0.f, c1 = 0.f, c2 = 0.f, c3 = 0.f, ca = 0.f;
    if (limit > 0) {
      float4 cb = *(const float4*)bxs[0];
      c0 = cb.x; c1 = cb.y; c2 = cb.z; c3 = cb.w; ca = sarea[0];
    }
    for (int i = 0; i < limit; i++) {
      int ip = (i + 1 < limit) ? (i + 1) : i;
      float4 nb = *(const float4*)bxs[ip];       // prefetch next (broadcast read)
      float na = sarea[ip];
      bool ov;
      {
        float iw = fmaxf(fminf(c2, k0x2) - fmaxf(c0, k0x1), 0.f);
        float ih = fmaxf(fminf(c3, k0y2) - fmaxf(c1, k0y1), 0.f);
        float inter = iw * ih;
        float uni = fmaxf(ca + k0a - inter, 1e-9f);
        ov = (lane < kept) && (inter / uni > 0.5f);
      }
      {
        float iw = fmaxf(fminf(c2, k1x2) - fmaxf(c0, k1x1), 0.f);
        float ih = fmaxf(fminf(c3, k1y2) - fmaxf(c1, k1y1), 0.f);
        float inter = iw * ih;
        float uni = fmaxf(ca + k1a - inter, 1e-9f);
        ov |= (64 + lane < kept) && (inter / uni > 0.5f);
      }
      if (!__any(ov)) {
        if (lane == (kept & 63)) {
          if (kept < 64) { k0x1 = c0; k0y1 = c1; k0x2 = c2; k0y2 = c3; k0a = ca; }
          else           { k1x1 = c0; k1y1 = c1; k1x2 = c2; k1y2 = c3; k1a = ca; }
        }
        if (lane == (i & 63)) keepbits |= (1u << (i >> 6));
        kept++;
        if (kept >= MAXPC) break;    // cumsum(keep) <= 100 drops anything later
      }
      c0 = nb.x; c1 = nb.y; c2 = nb.z; c3 = nb.w; ca = na;
    }
    // ---- ballot-based compaction positions
    uint32_t total = 0u;
    #pragma unroll
    for (int t = 0; t < 8; t++) {
      unsigned long long m = __ballot((int)((keepbits >> t) & 1u));
      uint32_t pre = total + (uint32_t)__popcll(m & ((1ull << lane) - 1ull));
      pos[t * 64 + lane] = ((keepbits >> t) & 1u) ? pre : 0xFFFFFFFFu;
      total += (uint32_t)__popcll(m);
    }
    if (lane == 0) selCount[bc] = (int)total;   // total <= 100 by construction
  }
  __syncthreads();

  // ---- write kept entries (order preserved)
  if (tid < 512) {
    uint32_t p = pos[tid];
    if (p < MAXPC) {
      selScore[bc * MAXPC + p] = __uint_as_float(skey[tid]);
      selRank[bc * MAXPC + p]  = tid;
      float* o = &selBox[(size_t)(bc * MAXPC + p) * 4];
      o[0] = bxs[tid][0]; o[1] = bxs[tid][1]; o[2] = bxs[tid][2]; o[3] = bxs[tid][3];
    }
  }
}

// ---------------------------------------------------------------- kernel 3
// per image: merge the two class lists (<=200 entries), exact top-100 by
// (score desc, flat index asc), write boxes/scores/classes/count.
__global__ __launch_bounds__(256) void merge_kernel(
    const float* __restrict__ selScore, const float* __restrict__ selBox,
    const int* __restrict__ selRank, const int* __restrict__ selCount,
    float* __restrict__ out)
{
  const int b   = blockIdx.x;
  const int tid = threadIdx.x;
  __shared__ float    es[256];
  __shared__ uint32_t ek[256];
  __shared__ float    eb[256][4];
  const int c0 = selCount[b * 2 + 0];
  const int c1 = selCount[b * 2 + 1];

  float s = -1.0f; uint32_t fk = 0xFFFFFFFFu;
  float bb[4] = {0.f, 0.f, 0.f, 0.f};
  if (tid < c0 + c1) {
    int cls  = (tid < c0) ? 0 : 1;
    int slot = (cls == 0) ? tid : (tid - c0);
    int src  = (b * 2 + cls) * MAXPC + slot;
    s  = selScore[src];
    fk = (uint32_t)(cls * KCAND + selRank[src]);   // flat index in (2,512) array
    bb[0] = selBox[(size_t)src * 4 + 0]; bb[1] = selBox[(size_t)src * 4 + 1];
    bb[2] = selBox[(size_t)src * 4 + 2]; bb[3] = selBox[(size_t)src * 4 + 3];
  }
  es[tid] = s; ek[tid] = fk;
  eb[tid][0] = bb[0]; eb[tid][1] = bb[1]; eb[tid][2] = bb[2]; eb[tid][3] = bb[3];
  __syncthreads();

  for (int kk = 2; kk <= 256; kk <<= 1) {
    for (int j = kk >> 1; j > 0; j >>= 1) {
      int ixj = tid ^ j;
      if (ixj > tid) {
        float sa = es[tid], sb = es[ixj];
        uint32_t fa = ek[tid], fb = ek[ixj];
        bool aLess = (sa < sb) || (sa == sb && fa > fb);
        if (((tid & kk) == 0) ? aLess : !aLess) {
          es[tid] = sb; es[ixj] = sa;
          ek[tid] = fb; ek[ixj] = fa;
          for (int d = 0; d < 4; d++) { float tmp = eb[tid][d]; eb[tid][d] = eb[ixj][d]; eb[ixj][d] = tmp; }
        }
      }
      __syncthreads();
    }
  }

  float* outBoxes  = out;
  float* outScores = out + (size_t)BATCH * MAXTOT * 4;
  float* outCls    = outScores + (size_t)BATCH * MAXTOT;
  float* outCnt    = outCls + (size_t)BATCH * MAXTOT;

  if (tid < MAXTOT) {
    float sc = es[tid];
    bool kept = sc > 0.0f;
    outScores[b * MAXTOT + tid] = kept ? sc : 0.0f;
    outCls[b * MAXTOT + tid]    = kept ? (float)(ek[tid] >> 9) : 0.0f;
    float* ob = &outBoxes[(size_t)(b * MAXTOT + tid) * 4];
    for (int d = 0; d < 4; d++) {
      float v = fminf(fmaxf(eb[tid][d], 0.f), 1.f);
      ob[d] = kept ? v : 0.0f;
    }
  }
  if (tid == 0) {
    int total = c0 + c1; if (total > MAXTOT) total = MAXTOT;
    outCnt[b] = (float)total;
  }
}

// ---------------------------------------------------------------- launch
extern "C" void kernel_launch(void* const* d_in, const int* in_sizes, int n_in,
                              void* d_out, int out_size, void* d_ws, size_t ws_size,
                              hipStream_t stream)
{
  const float* p1   = (const float*)d_in[0];
  const float* p2   = (const float*)d_in[1];
  const float* p3   = (const float*)d_in[2];
  const float* anch = (const float*)d_in[3];

  float* ws       = (float*)d_ws;
  float* scoresT  = ws;                                        // 64*2*22744 f32
  float* selScore = scoresT + (size_t)BATCH * 2 * NTOTP;       // 128*100 f32
  float* selBox   = selScore + BATCH * 2 * MAXPC;              // 128*100*4 f32
  int*   selRank  = (int*)(selBox + (size_t)BATCH * 2 * MAXPC * 4);
  int*   selCount = selRank + BATCH * 2 * MAXPC;               // 128 int

  const int total = BATCH * NTOT;
  score_kernel<<<(total + 255) / 256, 256, 0, stream>>>(p1, p2, p3, scoresT);
  nms_kernel<<<BATCH * 2, 512, 0, stream>>>(scoresT, p1, p2, p3, anch,
                                            selScore, selBox, selRank, selCount);
  merge_kernel<<<BATCH, 256, 0, stream>>>(selScore, selBox, selRank, selCount,
                                          (float*)d_out);
}